// Round 1
// baseline (138.627 us; speedup 1.0000x reference)
//
#include <hip/hip_runtime.h>
#include <hip/hip_bf16.h>

typedef __bf16 bf16x8 __attribute__((ext_vector_type(8)));
typedef float floatx4 __attribute__((ext_vector_type(4)));
typedef unsigned short u16;

#define HW 196   // 14*14
#define KP 224   // padded row length (elements), 7 k-blocks of 32
#define NB 8
#define NC 128

// ---- Stage 1: 1x1 conv (GEMM) + ReLU + 3x3 Gaussian blur (VALID) + bf16 cast ----
// grid (32, 8): o-group of 4 x batch. 256 threads = one per input pixel.
__global__ __launch_bounds__(256) void k_stage1(const float* __restrict__ x,
                                                const float* __restrict__ wc,
                                                __hip_bfloat16* __restrict__ xf) {
  const int og = blockIdx.x;       // 0..31
  const int b  = blockIdx.y;       // 0..7
  const int t  = threadIdx.x;      // pixel 0..255
  const float* xb = x + ((size_t)b * 512) * 256 + t;
  const float* w0 = wc + og * 4 * 512;   // wave-uniform index -> s_load

  float a0 = 0.f, a1 = 0.f, a2 = 0.f, a3 = 0.f;
#pragma unroll 8
  for (int i = 0; i < 512; ++i) {
    float xv = xb[(size_t)i * 256];
    a0 = fmaf(xv, w0[i], a0);
    a1 = fmaf(xv, w0[512 + i], a1);
    a2 = fmaf(xv, w0[1024 + i], a2);
    a3 = fmaf(xv, w0[1536 + i], a3);
  }

  __shared__ float ybuf[4][256];
  ybuf[0][t] = fmaxf(a0, 0.f);
  ybuf[1][t] = fmaxf(a1, 0.f);
  ybuf[2][t] = fmaxf(a2, 0.f);
  ybuf[3][t] = fmaxf(a3, 0.f);
  __syncthreads();

  // gaussian 3x3, variance 0.25: center 2/pi, edge *exp(-2), corner *exp(-4)
  const float GC = 0.63661977236758138f;
  const float GE = GC * 0.13533528323661270f;
  const float GD = GC * 0.018315638888734179f;

  if (t < KP) {
    int h = 0, w2 = 0;
    if (t < HW) { h = t / 14; w2 = t - h * 14; }
#pragma unroll
    for (int oo = 0; oo < 4; ++oo) {
      float v = 0.f;
      if (t < HW) {
        const float* yb = &ybuf[oo][h * 16 + w2];
        v = GD * (yb[0] + yb[2] + yb[32] + yb[34])
          + GE * (yb[1] + yb[16] + yb[18] + yb[33])
          + GC * yb[17];
      }
      // zero-fill [196,224) so K-padding contributes exactly 0 in stage 2
      xf[((b * NC + og * 4 + oo) * KP) + t] = __float2bfloat16(v);
    }
  }
}

// ---- Stage 2: circular convolution via MFMA + fold-4 max + atomicMax scatter ----
// grid (128, 8) = (c, b); 256 threads = 4 waves.
// R[a,c,p] = sum_i A[a,i] * ext_c[228 + p - i]   (ext = periodic row c, offset 32 guard)
// MFMA 16x16x32 bf16: A[m=lane&15][k=quad*8+j], B[k=quad*8+j][n=lane&15],
// D[m=quad*4+reg][n=lane&15]  (layouts per learn_hip m89/m120, HW-verified)
__global__ __launch_bounds__(256, 2) void k_cooc(const __hip_bfloat16* __restrict__ xf,
                                                 int* __restrict__ Rmax) {
  const int c = blockIdx.x;
  const int b = blockIdx.y;
  const int t = threadIdx.x;

  __shared__ __align__(16) u16 Abuf[NC * KP];   // 57344 B: all 128 rows of this batch
  __shared__ __align__(16) u16 ext[448];        // guarded periodic extension of row c

  {
    const uint4* src = (const uint4*)(xf + (size_t)b * NC * KP);
    uint4* dst = (uint4*)Abuf;
#pragma unroll
    for (int k = 0; k < 14; ++k) dst[t + 256 * k] = src[t + 256 * k];
  }
  __syncthreads();
  for (int j = t; j < 448; j += 256) {
    int idx = (j + 360) % 196;    // periodic: j=32 -> element 0; guard region finite
    ext[j] = Abuf[c * KP + idx];
  }
  __syncthreads();

  const int lane = t & 63;
  const int wv   = t >> 6;        // wave 0..3; p-tiles {wv, wv+4, wv+8} (+12 for wave 0)
  const int n    = lane & 15;
  const int quad = lane >> 4;

  floatx4 acc[8][4];
#pragma unroll
  for (int at = 0; at < 8; ++at)
#pragma unroll
    for (int j = 0; j < 4; ++j) acc[at][j] = (floatx4){0.f, 0.f, 0.f, 0.f};

  const int arow_off = n * KP + quad * 8;

  for (int kb = 0; kb < 7; ++kb) {
    const int i0 = kb * 32;
    bf16x8 af[8];
#pragma unroll
    for (int at = 0; at < 8; ++at)
      af[at] = *((const bf16x8*)&Abuf[(at * 16) * KP + arow_off + i0]);   // ds_read_b128

#define DO_PT(JC)                                                               \
    {                                                                           \
      const int p = (wv + 4 * (JC)) * 16 + n;                                   \
      const int base = 228 + p - i0 - quad * 8;                                 \
      union { u16 u[8]; bf16x8 v; } bu;                                         \
      _Pragma("unroll")                                                         \
      for (int jj = 0; jj < 8; ++jj) bu.u[jj] = ext[base - jj];                 \
      _Pragma("unroll")                                                         \
      for (int at = 0; at < 8; ++at)                                            \
        acc[at][JC] = __builtin_amdgcn_mfma_f32_16x16x32_bf16(af[at], bu.v,     \
                                                              acc[at][JC], 0, 0, 0); \
    }

    DO_PT(0)
    DO_PT(1)
    DO_PT(2)
    if (wv == 0) { DO_PT(3) }
#undef DO_PT
  }

  // epilogue: r = ((a*128+c)*196+p) mod 16384; a and a+32k fold to the same r
  int* Rb = Rmax + b * 16384;

#define EPI(JC)                                                                 \
  {                                                                             \
    const int p = (wv + 4 * (JC)) * 16 + n;                                     \
    if (p < HW) {                                                               \
      _Pragma("unroll")                                                         \
      for (int a0t = 0; a0t < 2; ++a0t) {                                       \
        _Pragma("unroll")                                                       \
        for (int rr = 0; rr < 4; ++rr) {                                        \
          float v = fmaxf(fmaxf(acc[a0t][JC][rr], acc[a0t + 2][JC][rr]),        \
                          fmaxf(acc[a0t + 4][JC][rr], acc[a0t + 6][JC][rr]));   \
          int a1 = a0t * 16 + quad * 4 + rr;                                    \
          int F = (a1 * 128 + c) * 196 + p;                                     \
          atomicMax(Rb + (F & 16383), __float_as_int(v));  /* v >= 0 always */  \
        }                                                                       \
      }                                                                         \
    }                                                                           \
  }

  EPI(0)
  EPI(1)
  EPI(2)
  if (wv == 0) { EPI(3) }
#undef EPI
}

// ---- Stage 3: per-batch norm + sqrt + divide ----
__global__ __launch_bounds__(256) void k_final(const int* __restrict__ Rmax,
                                               float* __restrict__ out) {
  const int b = blockIdx.x;
  const int t = threadIdx.x;
  const int* Rb = Rmax + b * 16384;
  float s = 0.f;
  for (int r = t; r < 16384; r += 256) s += __int_as_float(Rb[r]);
#pragma unroll
  for (int off = 32; off > 0; off >>= 1) s += __shfl_down(s, off, 64);
  __shared__ float part[4];
  if ((t & 63) == 0) part[t >> 6] = s;
  __syncthreads();
  const float tot = part[0] + part[1] + part[2] + part[3] + 1e-11f;
  const float inv = 1.0f / tot;
  float* ob = out + b * 16384;
  for (int r = t; r < 16384; r += 256) ob[r] = sqrtf(__int_as_float(Rb[r])) * inv;
}

extern "C" void kernel_launch(void* const* d_in, const int* in_sizes, int n_in,
                              void* d_out, int out_size, void* d_ws, size_t ws_size,
                              hipStream_t stream) {
  const float* x  = (const float*)d_in[0];   // (8,512,16,16) fp32
  const float* wc = (const float*)d_in[1];   // (128,512) fp32
  __hip_bfloat16* xf = (__hip_bfloat16*)d_ws;                      // 458752 B
  int* Rmax = (int*)((char*)d_ws + (size_t)NB * NC * KP * 2);      // 524288 B

  hipMemsetAsync(Rmax, 0, (size_t)NB * 16384 * sizeof(int), stream);
  k_stage1<<<dim3(32, 8), 256, 0, stream>>>(x, wc, xf);
  k_cooc<<<dim3(128, 8), 256, 0, stream>>>(xf, Rmax);
  k_final<<<8, 256, 0, stream>>>(Rmax, (float*)d_out);
}